// Round 8
// baseline (437.328 us; speedup 1.0000x reference)
//
#include <hip/hip_runtime.h>

#define N_NODES 100000
#define IN_F    256
#define OUT_F   64
#define D_CH    4
#define N_EDGE  800000
#define M_SEG   (D_CH * N_NODES)          // 400000 segments
#define CPW     16                         // chains per wave

typedef __attribute__((ext_vector_type(8))) short short8;
typedef __attribute__((ext_vector_type(4))) float f32x4;

__device__ inline ushort f2bf(float f) {           // round-to-nearest-even
    union { float f; unsigned u; } v; v.f = f;
    unsigned b = v.u + 0x7FFFu + ((v.u >> 16) & 1u);
    return (ushort)(b >> 16);
}
__device__ inline float bf2f(ushort u) {
    union { unsigned u; float f; } v; v.u = ((unsigned)u) << 16;
    return v.f;
}
__device__ inline float bits2f(int b) {
    union { int i; float f; } v; v.i = b; return v.f;
}

// ---------------------------------------------------------------------------
// One-time: repack W (f32) into per-lane bf16 MFMA B-fragments.
// Fragment (i, ks, nt): lane l, elem j holds W[i][ks*32 + (l>>4)*8 + j][nt*16 + (l&15)]
// ---------------------------------------------------------------------------
__global__ __launch_bounds__(256) void bpack_kernel(
    const float* __restrict__ W, ushort* __restrict__ Bpack)
{
    const int t = blockIdx.x * 256 + threadIdx.x;      // 0 .. 8191
    if (t >= D_CH * 8 * 4 * 64) return;
    const int l  = t & 63;
    const int nt = (t >> 6) & 3;
    const int ks = (t >> 8) & 7;
    const int i  = t >> 11;
    const int n  = nt * 16 + (l & 15);
    const int k0 = ks * 32 + (l >> 4) * 8;
    ushort v[8];
#pragma unroll
    for (int j = 0; j < 8; ++j)
        v[j] = f2bf(W[((size_t)i * IN_F + k0 + j) * OUT_F + n]);
#pragma unroll
    for (int j = 0; j < 8; ++j)
        Bpack[(size_t)t * 8 + j] = v[j];
}

// ---------------------------------------------------------------------------
// MFMA GEMM + fused pvec epilogue.  (unchanged from R6/R7)
// C/D layout (HW-verified): col = lane&15, row = (lane>>4)*4 + reg.
// ---------------------------------------------------------------------------
__global__ __launch_bounds__(256) void gemm_mfma_kernel(
    const float* __restrict__ feature, const float* __restrict__ norm,
    const ushort* __restrict__ Bpack, const float* __restrict__ att_w,
    ushort* __restrict__ Wh_b, float* __restrict__ p_src, float* __restrict__ p_dst)
{
    const int wv   = threadIdx.x >> 6;
    const int lane = threadIdx.x & 63;
    const int kg   = lane >> 4;
    const int cl   = lane & 15;
    const int r0   = blockIdx.x * 64 + wv * 16;

    const int rowm   = r0 + cl;
    const int rclamp = (rowm < N_NODES) ? rowm : (N_NODES - 1);
    const float* __restrict__ arow = feature + (size_t)rclamp * IN_F + kg * 8;
    short8 afrag[8];
#pragma unroll
    for (int ks = 0; ks < 8; ++ks) {
        const f32x4 x = *(const f32x4*)(arow + ks * 32);
        const f32x4 y = *(const f32x4*)(arow + ks * 32 + 4);
        short8 a;
        a[0] = (short)f2bf(x[0]); a[1] = (short)f2bf(x[1]);
        a[2] = (short)f2bf(x[2]); a[3] = (short)f2bf(x[3]);
        a[4] = (short)f2bf(y[0]); a[5] = (short)f2bf(y[1]);
        a[6] = (short)f2bf(y[2]); a[7] = (short)f2bf(y[3]);
        afrag[ks] = a;
    }

    float pa[4], pb[4];
#pragma unroll
    for (int nt = 0; nt < 4; ++nt) {
        pa[nt] = att_w[nt * 16 + cl];
        pb[nt] = att_w[OUT_F + nt * 16 + cl];
    }
    float nm[4];
    bool  rvld[4];
#pragma unroll
    for (int r = 0; r < 4; ++r) {
        const int rr = r0 + kg * 4 + r;
        rvld[r] = rr < N_NODES;
        nm[r] = rvld[r] ? norm[rr] : 0.f;
    }

    const short8* __restrict__ bp = (const short8*)Bpack;

    for (int i = 0; i < D_CH; ++i) {
        f32x4 acc[4];
#pragma unroll
        for (int nt = 0; nt < 4; ++nt) acc[nt] = (f32x4){0.f, 0.f, 0.f, 0.f};

#pragma unroll
        for (int ks = 0; ks < 8; ++ks) {
#pragma unroll
            for (int nt = 0; nt < 4; ++nt) {
                const short8 bf = bp[((((i * 8) + ks) * 4 + nt) << 6) + lane];
                acc[nt] = __builtin_amdgcn_mfma_f32_16x16x32_bf16(
                    afrag[ks], bf, acc[nt], 0, 0, 0);
            }
        }

        float ps[4] = {0.f, 0.f, 0.f, 0.f}, pd[4] = {0.f, 0.f, 0.f, 0.f};
#pragma unroll
        for (int nt = 0; nt < 4; ++nt) {
#pragma unroll
            for (int r = 0; r < 4; ++r) {
                const float v = acc[nt][r] * nm[r];
                const int rr = r0 + kg * 4 + r;
                if (rvld[r])
                    Wh_b[((size_t)i * N_NODES + rr) * OUT_F + nt * 16 + cl] = f2bf(v);
                ps[r] += v * pa[nt];
                pd[r] += v * pb[nt];
            }
        }
#pragma unroll
        for (int r = 0; r < 4; ++r) {
            float s1 = ps[r], s2 = pd[r];
#pragma unroll
            for (int off = 1; off < 16; off <<= 1) {
                s1 += __shfl_xor(s1, off, 64);
                s2 += __shfl_xor(s2, off, 64);
            }
            if (cl == 0 && rvld[r]) {
                const int rr = r0 + kg * 4 + r;
                p_src[i * N_NODES + rr] = s1;
                p_dst[i * N_NODES + rr] = s2;
            }
        }
    }
}

// ---------------------------------------------------------------------------
// Linked-list build with FULL records: rec[i][e] = {next, s<<7, w_bits, 0}.
// s<<7 = byte offset of row s in the bf16 Wh slab (64 * 2B = 128B rows),
// so agg does a single byte-add for the gather address.
// rec writes are SEQUENTIAL 16B. Must run after gemm (needs p_src/p_dst).
// ---------------------------------------------------------------------------
__global__ __launch_bounds__(256) void build_kernel(
    const int* __restrict__ src, const int* __restrict__ dst,
    const float* __restrict__ p_src, const float* __restrict__ p_dst,
    int* __restrict__ head, int4* __restrict__ rec)
{
    const int e = blockIdx.x * 256 + threadIdx.x;
    const int i = blockIdx.y;
    const int d = dst[(size_t)i * N_EDGE + e];
    const int s = src[(size_t)i * N_EDGE + e];
    float x = p_src[i * N_NODES + s] + p_dst[i * N_NODES + d];
    x = (x > 0.f) ? x : 0.2f * x;
    const float w = __expf(x);   // max-free softmax: logits O(4), no overflow
    union { float f; int i; } wb; wb.f = w;
    const int old = atomicExch(&head[i * N_NODES + d], e);
    rec[(size_t)i * N_EDGE + e] = make_int4(old, s << 7, wb.i, 0);
}

// ---------------------------------------------------------------------------
// Aggregate via linked lists, CPW=16 chains/wave, ONE wait point per iter.
// Iter k: per chain issue TWO independent loads (Wh row gather via byte
// offset, rec of next edge) -> 32 loads in flight/wave; accumulate; ingest.
// Iterations/wave = max chain length over 16 chains ~ 14.5 for Po(8)
// -> 0.91 iter/segment (was 1.63 at CPW=8): ~45% fewer exposed latencies.
// ---------------------------------------------------------------------------
__global__ __launch_bounds__(256) void agg_ll_kernel(
    const int* __restrict__ head, const int4* __restrict__ rec,
    const ushort* __restrict__ Wh_b, const float* __restrict__ norm,
    float* __restrict__ out)
{
    const int wv   = threadIdx.x >> 6;
    const int lane = threadIdx.x & 63;
    const int g0   = (blockIdx.x * 4 + wv) * CPW;   // 16 consecutive segments
    // N_NODES % CPW == 0 -> all CPW segments share one channel.
    const int i  = g0 / N_NODES;
    const int n0 = g0 - i * N_NODES;

    const int4* __restrict__ recb = rec + (size_t)i * N_EDGE;
    const char* __restrict__ whb  =
        (const char*)(Wh_b + (size_t)i * N_NODES * OUT_F + lane);

    // ---- prologue: ingest head edge of each chain ----
    int   sb[CPW], en[CPW];
    float w[CPW], acc[CPW], z[CPW];
#pragma unroll
    for (int c = 0; c < CPW; ++c) {
        const int h = head[g0 + c];
        const int4 r = recb[(h >= 0) ? h : 0];
        const bool live = (h >= 0);
        sb[c]  = live ? r.y : 0;
        w[c]   = live ? bits2f(r.z) : 0.f;
        en[c]  = live ? r.x : -1;
        acc[c] = 0.f;
        z[c]   = 0.f;
    }

    for (;;) {
        int pending = 0;
#pragma unroll
        for (int c = 0; c < CPW; ++c) {
            // two independent loads -> single wait covers both
            const float wh = bf2f(*(const ushort*)(whb + sb[c]));
            const int4  r  = recb[(en[c] >= 0) ? en[c] : 0];

            acc[c] += w[c] * wh;     // w==0 for dead chains: harmless
            z[c]   += w[c];

            const int live = (en[c] >= 0);
            sb[c] = live ? r.y : 0;
            w[c]  = live ? bits2f(r.z) : 0.f;
            en[c] = live ? r.x : -1;
            pending |= live;
        }
        if (!pending) break;
    }

#pragma unroll
    for (int c = 0; c < CPW; ++c) {
        const int n = n0 + c;
        float v = (z[c] > 0.f) ? (acc[c] / z[c]) * norm[n] : 0.f;
        out[(size_t)n * (D_CH * OUT_F) + i * OUT_F + lane] = (v > 0.f) ? v : 0.f;
    }
}

// ---------------------------------------------------------------------------
extern "C" void kernel_launch(void* const* d_in, const int* in_sizes, int n_in,
                              void* d_out, int out_size, void* d_ws, size_t ws_size,
                              hipStream_t stream)
{
    const float* feature = (const float*)d_in[0];
    const float* norm    = (const float*)d_in[1];
    const float* W       = (const float*)d_in[2];
    const float* att_w   = (const float*)d_in[3];
    const int*   src     = (const int*)d_in[4];
    const int*   dst     = (const int*)d_in[5];
    float* out = (float*)d_out;

    // Workspace layout:
    // Wh_b[25.6M u16 = 51.2MB] | p_src[400K f] | p_dst[400K f] |
    // head[400K i] | rec[3.2M int4 = 51.2MB] | Bpack[65536 u16]  total ~= 108 MB
    ushort* Wh_b  = (ushort*)d_ws;
    float*  p_src = (float*)(Wh_b + (size_t)M_SEG * OUT_F);
    float*  p_dst = p_src + M_SEG;
    int*    head  = (int*)(p_dst + M_SEG);
    int4*   rec   = (int4*)(head + M_SEG);
    ushort* Bpack = (ushort*)(rec + (size_t)D_CH * N_EDGE);

    bpack_kernel<<<dim3(32), 256, 0, stream>>>(W, Bpack);
    gemm_mfma_kernel<<<dim3((N_NODES + 63) / 64), 256, 0, stream>>>(
        feature, norm, Bpack, att_w, Wh_b, p_src, p_dst);

    hipMemsetAsync(head, 0xFF, (size_t)M_SEG * sizeof(int), stream);  // head = -1
    build_kernel<<<dim3(N_EDGE / 256, D_CH), 256, 0, stream>>>(
        src, dst, p_src, p_dst, head, rec);
    agg_ll_kernel<<<dim3(M_SEG / (4 * CPW)), 256, 0, stream>>>(
        head, rec, Wh_b, norm, out);
}

// Round 9
// 394.862 us; speedup vs baseline: 1.1075x; 1.1075x over previous
//
#include <hip/hip_runtime.h>
#include <hip/hip_bf16.h>

#define N_NODES 100000
#define IN_F    256
#define OUT_F   64
#define D_CH    4
#define N_EDGE  800000
#define M_SEG   (D_CH * N_NODES)          // 400000 segments
#define CPW     8                          // chains per wave (R7-proven optimum)

typedef __attribute__((ext_vector_type(8))) short short8;
typedef __attribute__((ext_vector_type(4))) float f32x4;

__device__ inline ushort f2bf(float f) {           // round-to-nearest-even
    union { float f; unsigned u; } v; v.f = f;
    unsigned b = v.u + 0x7FFFu + ((v.u >> 16) & 1u);
    return (ushort)(b >> 16);
}
__device__ inline float bf2f(ushort u) {
    union { unsigned u; float f; } v; v.u = ((unsigned)u) << 16;
    return v.f;
}
__device__ inline float bits2f(int b) {
    union { int i; float f; } v; v.i = b; return v.f;
}
// native paired f32->bf16 (compiler emits v_cvt_pk_bf16_f32; RNE)
__device__ inline void cvt2(float a, float b, ushort& lo, ushort& hi) {
    __hip_bfloat162 h = __float22bfloat162_rn(float2{a, b});
    union { __hip_bfloat162 h; ushort2 u; } v; v.h = h;
    lo = v.u.x; hi = v.u.y;
}

// ---------------------------------------------------------------------------
// One-time: repack W (f32) into per-lane bf16 MFMA B-fragments.
// Fragment (i, ks, nt): lane l, elem j holds W[i][ks*32 + (l>>4)*8 + j][nt*16 + (l&15)]
// ---------------------------------------------------------------------------
__global__ __launch_bounds__(256) void bpack_kernel(
    const float* __restrict__ W, ushort* __restrict__ Bpack)
{
    const int t = blockIdx.x * 256 + threadIdx.x;      // 0 .. 8191
    if (t >= D_CH * 8 * 4 * 64) return;
    const int l  = t & 63;
    const int nt = (t >> 6) & 3;
    const int ks = (t >> 8) & 7;
    const int i  = t >> 11;
    const int n  = nt * 16 + (l & 15);
    const int k0 = ks * 32 + (l >> 4) * 8;
    ushort v[8];
#pragma unroll
    for (int j = 0; j < 8; ++j)
        v[j] = f2bf(W[((size_t)i * IN_F + k0 + j) * OUT_F + n]);
#pragma unroll
    for (int j = 0; j < 8; ++j)
        Bpack[(size_t)t * 8 + j] = v[j];
}

// ---------------------------------------------------------------------------
// MFMA GEMM + fused pvec epilogue. Native cvt_pk bf16 conversions.
// C/D layout (HW-verified): col = lane&15, row = (lane>>4)*4 + reg.
// ---------------------------------------------------------------------------
__global__ __launch_bounds__(256) void gemm_mfma_kernel(
    const float* __restrict__ feature, const float* __restrict__ norm,
    const ushort* __restrict__ Bpack, const float* __restrict__ att_w,
    ushort* __restrict__ Wh_b, float* __restrict__ p_src, float* __restrict__ p_dst)
{
    const int wv   = threadIdx.x >> 6;
    const int lane = threadIdx.x & 63;
    const int kg   = lane >> 4;
    const int cl   = lane & 15;
    const int r0   = blockIdx.x * 64 + wv * 16;

    const int rowm   = r0 + cl;
    const int rclamp = (rowm < N_NODES) ? rowm : (N_NODES - 1);
    const float* __restrict__ arow = feature + (size_t)rclamp * IN_F + kg * 8;
    short8 afrag[8];
#pragma unroll
    for (int ks = 0; ks < 8; ++ks) {
        const f32x4 x = *(const f32x4*)(arow + ks * 32);
        const f32x4 y = *(const f32x4*)(arow + ks * 32 + 4);
        ushort u[8];
        cvt2(x[0], x[1], u[0], u[1]);
        cvt2(x[2], x[3], u[2], u[3]);
        cvt2(y[0], y[1], u[4], u[5]);
        cvt2(y[2], y[3], u[6], u[7]);
        short8 a;
#pragma unroll
        for (int j = 0; j < 8; ++j) a[j] = (short)u[j];
        afrag[ks] = a;
    }

    float pa[4], pb[4];
#pragma unroll
    for (int nt = 0; nt < 4; ++nt) {
        pa[nt] = att_w[nt * 16 + cl];
        pb[nt] = att_w[OUT_F + nt * 16 + cl];
    }
    float nm[4];
    bool  rvld[4];
#pragma unroll
    for (int r = 0; r < 4; ++r) {
        const int rr = r0 + kg * 4 + r;
        rvld[r] = rr < N_NODES;
        nm[r] = rvld[r] ? norm[rr] : 0.f;
    }

    const short8* __restrict__ bp = (const short8*)Bpack;

    for (int i = 0; i < D_CH; ++i) {
        f32x4 acc[4];
#pragma unroll
        for (int nt = 0; nt < 4; ++nt) acc[nt] = (f32x4){0.f, 0.f, 0.f, 0.f};

#pragma unroll
        for (int ks = 0; ks < 8; ++ks) {
#pragma unroll
            for (int nt = 0; nt < 4; ++nt) {
                const short8 bf = bp[((((i * 8) + ks) * 4 + nt) << 6) + lane];
                acc[nt] = __builtin_amdgcn_mfma_f32_16x16x32_bf16(
                    afrag[ks], bf, acc[nt], 0, 0, 0);
            }
        }

        // epilogue: ×norm, paired cvt + bf16 Wh store, p partial dots
        float vv[4][4];
        float ps[4] = {0.f, 0.f, 0.f, 0.f}, pd[4] = {0.f, 0.f, 0.f, 0.f};
#pragma unroll
        for (int nt = 0; nt < 4; ++nt) {
#pragma unroll
            for (int r = 0; r < 4; ++r) {
                const float v = acc[nt][r] * nm[r];
                vv[nt][r] = v;
                ps[r] += v * pa[nt];
                pd[r] += v * pb[nt];
            }
        }
#pragma unroll
        for (int r = 0; r < 4; ++r) {
            const int rr = r0 + kg * 4 + r;
            if (!rvld[r]) continue;
            ushort u0, u1, u2, u3;
            cvt2(vv[0][r], vv[1][r], u0, u1);
            cvt2(vv[2][r], vv[3][r], u2, u3);
            ushort* wrow = Wh_b + ((size_t)i * N_NODES + rr) * OUT_F + cl;
            wrow[0]  = u0;
            wrow[16] = u1;
            wrow[32] = u2;
            wrow[48] = u3;
        }
#pragma unroll
        for (int r = 0; r < 4; ++r) {
            float s1 = ps[r], s2 = pd[r];
#pragma unroll
            for (int off = 1; off < 16; off <<= 1) {
                s1 += __shfl_xor(s1, off, 64);
                s2 += __shfl_xor(s2, off, 64);
            }
            if (cl == 0 && rvld[r]) {
                const int rr = r0 + kg * 4 + r;
                p_src[i * N_NODES + rr] = s1;
                p_dst[i * N_NODES + rr] = s2;
            }
        }
    }
}

// ---------------------------------------------------------------------------
// Linked-list build with FULL records: rec[i][e] = {next, s<<7, w_bits, 0}.
// s<<7 = byte offset of row s in the bf16 Wh slab (64 * 2B = 128B rows).
// rec writes are SEQUENTIAL 16B. Must run after gemm (needs p_src/p_dst).
// ---------------------------------------------------------------------------
__global__ __launch_bounds__(256) void build_kernel(
    const int* __restrict__ src, const int* __restrict__ dst,
    const float* __restrict__ p_src, const float* __restrict__ p_dst,
    int* __restrict__ head, int4* __restrict__ rec)
{
    const int e = blockIdx.x * 256 + threadIdx.x;
    const int i = blockIdx.y;
    const int d = dst[(size_t)i * N_EDGE + e];
    const int s = src[(size_t)i * N_EDGE + e];
    float x = p_src[i * N_NODES + s] + p_dst[i * N_NODES + d];
    x = (x > 0.f) ? x : 0.2f * x;
    const float w = __expf(x);   // max-free softmax: logits O(4), no overflow
    union { float f; int i; } wb; wb.f = w;
    const int old = atomicExch(&head[i * N_NODES + d], e);
    rec[(size_t)i * N_EDGE + e] = make_int4(old, s << 7, wb.i, 0);
}

// ---------------------------------------------------------------------------
// Aggregate via linked lists, CPW=8 chains/wave, ONE wait point per iter.
// Per chain per iter: TWO independent loads (Wh row gather via byte offset,
// rec of next edge) -> 16 in flight/wave; accumulate; ingest. R7-proven.
// ---------------------------------------------------------------------------
__global__ __launch_bounds__(256) void agg_ll_kernel(
    const int* __restrict__ head, const int4* __restrict__ rec,
    const ushort* __restrict__ Wh_b, const float* __restrict__ norm,
    float* __restrict__ out)
{
    const int wv   = threadIdx.x >> 6;
    const int lane = threadIdx.x & 63;
    const int g0   = (blockIdx.x * 4 + wv) * CPW;   // 8 consecutive segments
    // N_NODES % CPW == 0 -> all CPW segments share one channel.
    const int i  = g0 / N_NODES;
    const int n0 = g0 - i * N_NODES;

    const int4* __restrict__ recb = rec + (size_t)i * N_EDGE;
    const char* __restrict__ whb  =
        (const char*)(Wh_b + (size_t)i * N_NODES * OUT_F + lane);

    // ---- prologue: ingest head edge of each chain ----
    int   sb[CPW], en[CPW];
    float w[CPW], acc[CPW], z[CPW];
#pragma unroll
    for (int c = 0; c < CPW; ++c) {
        const int h = head[g0 + c];
        const int4 r = recb[(h >= 0) ? h : 0];
        const bool live = (h >= 0);
        sb[c]  = live ? r.y : 0;
        w[c]   = live ? bits2f(r.z) : 0.f;
        en[c]  = live ? r.x : -1;
        acc[c] = 0.f;
        z[c]   = 0.f;
    }

    for (;;) {
        int pending = 0;
#pragma unroll
        for (int c = 0; c < CPW; ++c) {
            // two independent loads -> single wait covers both
            const float wh = bf2f(*(const ushort*)(whb + sb[c]));
            const int4  r  = recb[(en[c] >= 0) ? en[c] : 0];

            acc[c] += w[c] * wh;     // w==0 for dead chains: harmless
            z[c]   += w[c];

            const int live = (en[c] >= 0);
            sb[c] = live ? r.y : 0;
            w[c]  = live ? bits2f(r.z) : 0.f;
            en[c] = live ? r.x : -1;
            pending |= live;
        }
        if (!pending) break;
    }

#pragma unroll
    for (int c = 0; c < CPW; ++c) {
        const int n = n0 + c;
        float v = (z[c] > 0.f) ? (acc[c] / z[c]) * norm[n] : 0.f;
        out[(size_t)n * (D_CH * OUT_F) + i * OUT_F + lane] = (v > 0.f) ? v : 0.f;
    }
}

// ---------------------------------------------------------------------------
extern "C" void kernel_launch(void* const* d_in, const int* in_sizes, int n_in,
                              void* d_out, int out_size, void* d_ws, size_t ws_size,
                              hipStream_t stream)
{
    const float* feature = (const float*)d_in[0];
    const float* norm    = (const float*)d_in[1];
    const float* W       = (const float*)d_in[2];
    const float* att_w   = (const float*)d_in[3];
    const int*   src     = (const int*)d_in[4];
    const int*   dst     = (const int*)d_in[5];
    float* out = (float*)d_out;

    // Workspace layout:
    // Wh_b[25.6M u16 = 51.2MB] | p_src[400K f] | p_dst[400K f] |
    // head[400K i] | rec[3.2M int4 = 51.2MB] | Bpack[65536 u16]  total ~= 108 MB
    ushort* Wh_b  = (ushort*)d_ws;
    float*  p_src = (float*)(Wh_b + (size_t)M_SEG * OUT_F);
    float*  p_dst = p_src + M_SEG;
    int*    head  = (int*)(p_dst + M_SEG);
    int4*   rec   = (int4*)(head + M_SEG);
    ushort* Bpack = (ushort*)(rec + (size_t)D_CH * N_EDGE);

    bpack_kernel<<<dim3(32), 256, 0, stream>>>(W, Bpack);
    gemm_mfma_kernel<<<dim3((N_NODES + 63) / 64), 256, 0, stream>>>(
        feature, norm, Bpack, att_w, Wh_b, p_src, p_dst);

    hipMemsetAsync(head, 0xFF, (size_t)M_SEG * sizeof(int), stream);  // head = -1
    build_kernel<<<dim3(N_EDGE / 256, D_CH), 256, 0, stream>>>(
        src, dst, p_src, p_dst, head, rec);
    agg_ll_kernel<<<dim3(M_SEG / (4 * CPW)), 256, 0, stream>>>(
        head, rec, Wh_b, norm, out);
}